// Round 20
// baseline (181.770 us; speedup 1.0000x reference)
//
#include <hip/hip_runtime.h>

#define NB    4
#define NPTS  4096
#define DF    32      // D*C
#define CC    8
#define CO    16
#define KNN   16
#define NG    (NPTS/64)   // 64 candidate groups per batch
#define FIFO_N 128    // per-row pending ring (max pending 63+64=127)
#define QS    21.0f   // i8 quant scale (127/6 sigma; data N(0,1), no clipping)
#define BIAS  (1 << 21)
#define RPW   4       // rows per wave (R20: amortize fixed costs)

__device__ __forceinline__ int q8(float x) {
    int v = __float2int_rn(x * QS);
    return v < -127 ? -127 : (v > 127 ? 127 : v);
}
__device__ __forceinline__ int dot4i8(unsigned a, unsigned b, int acc) {
#if __has_builtin(__builtin_amdgcn_sdot4)
    return __builtin_amdgcn_sdot4((int)a, (int)b, acc, false);
#else
    int s = acc;
#pragma unroll
    for (int i = 0; i < 4; ++i)
        s += (int)(char)((a >> (8 * i)) & 255) * (int)(char)((b >> (8 * i)) & 255);
    return s;
#endif
}

// Full-wave ascending bitonic sort of one u32 per lane (verified R3-R19).
__device__ __forceinline__ unsigned bitonic_sort64(unsigned key, int lane) {
#pragma unroll
    for (int k = 2; k <= 64; k <<= 1) {
#pragma unroll
        for (int j = k >> 1; j > 0; j >>= 1) {
            unsigned o = __shfl_xor(key, j);
            bool up       = ((lane & k) == 0);
            bool lower    = ((lane & j) == 0);
            bool takeMin  = (lower == up);
            bool mineLess = key < o;
            if (takeMin != mineLess) key = o;
        }
    }
    return key;
}
__device__ __forceinline__ unsigned bitonic_clean64(unsigned v, int lane) {
#pragma unroll
    for (int j = 32; j > 0; j >>= 1) {
        unsigned o = __shfl_xor(v, j);
        bool lower = ((lane & j) == 0);
        v = lower ? min(v, o) : max(v, o);
    }
    return v;
}
__device__ __forceinline__ void merge_batch(unsigned& run, unsigned bk, int lane) {
    bk = bitonic_sort64(bk, lane);
    unsigned rev = __shfl(bk, 63 - lane);
    unsigned lo  = min(run, rev);
    run = bitonic_clean64(lo, lane);
}

// ---- prep: pre-biased integer sq + group-transposed i8 layout ----
__global__ void prep_kernel(const float* __restrict__ x, int* __restrict__ sqi,
                            uint4* __restrict__ xt) {
    int i = blockIdx.x * 256 + threadIdx.x;          // 0 .. NB*NPTS-1
    const int b = i >> 12, n = i & (NPTS - 1);
    const int g = n >> 6,  l = n & 63;
    const float* p = x + (size_t)i * DF;
    int s = 0;
    unsigned pk[8];
#pragma unroll
    for (int j = 0; j < 8; ++j) {
        int q0 = q8(p[4*j+0]), q1 = q8(p[4*j+1]);
        int q2 = q8(p[4*j+2]), q3 = q8(p[4*j+3]);
        s += q0*q0 + q1*q1 + q2*q2 + q3*q3;
        pk[j] = (unsigned)(q0 & 255) | ((unsigned)(q1 & 255) << 8)
              | ((unsigned)(q2 & 255) << 16) | ((unsigned)(q3 & 255) << 24);
    }
    uint4* ho = xt + ((size_t)(b * NG + g) * 2) * 64 + l;
    ho[0]  = make_uint4(pk[0], pk[1], pk[2], pk[3]);
    ho[64] = make_uint4(pk[4], pk[5], pk[6], pk[7]);
    sqi[i] = s + BIAS;                   // pre-biased: key_d = sqi - 2*dot > 0
}

// ---- canonical-fp32 re-rank + output (verified R3-R19 verbatim) ----
__device__ __forceinline__ void rerank_and_emit(
    unsigned runv, int nn, const float* __restrict__ xb,
    const float (*w1n)[KNN], const float (*w2n)[CO],
    float* __restrict__ out, int bb, int lane) {

    int mym = (int)(runv & 0xFFFu);
    const float* rp = xb + (size_t)nn * DF;
    const float* cp = xb + (size_t)mym * DF;
    double dot64 = 0.0, sqm64 = 0.0, sqn64 = 0.0;
#pragma unroll
    for (int f = 0; f < DF; ++f) {
        double cv = (double)cp[f];
        double rv = (double)rp[f];
        dot64 = fma(rv, cv, dot64);
        sqm64 = fma(cv, cv, sqm64);
        sqn64 = fma(rv, rv, sqn64);
    }
    float dist32 = ((float)sqn64 + (float)sqm64) - 2.0f * (float)dot64;

    unsigned sortd;
    {
        unsigned u = __float_as_uint(dist32);
        sortd = u ^ ((unsigned)((int)u >> 31) | 0x80000000u);
    }
    unsigned long long key =
        ((unsigned long long)sortd << 32) | (unsigned)mym;
#pragma unroll
    for (int k = 2; k <= 64; k <<= 1) {
#pragma unroll
        for (int j = k >> 1; j > 0; j >>= 1) {
            unsigned long long ok = __shfl_xor(key, j);
            bool up       = ((lane & k) == 0);
            bool lower    = ((lane & j) == 0);
            bool takeMin  = (lower == up);
            bool mineLess = (key < ok);
            if (takeMin != mineLess) key = ok;
        }
    }
    mym = (int)(key & 0xFFFFFFFFull);

    float wsum = 0.f;
#pragma unroll
    for (int k = 0; k < KNN; ++k) {
        int mk = __shfl(mym, k);                       // uniform
        float v = 0.f;
        if (lane < DF) v = xb[(size_t)mk * DF + lane]; // coalesced gather
        wsum = fmaf(v, w1n[lane & 7][k], wsum);        // lane = d*8+c
    }
    float ov = 0.f;
    const int d_ = lane >> 4, o_ = lane & 15;
#pragma unroll
    for (int c = 0; c < CC; ++c) {
        float wv = __shfl(wsum, d_ * CC + c);
        ov = fmaf(wv, w2n[c][o_], ov);
    }
    out[(size_t)(bb * NPTS + nn) * (4 * CO) + lane] = ov;
}

// ======== barrier-free i8 scan, 4 rows/wave fixed-cost amortized (R20) =====
__global__ __launch_bounds__(256)
void wfm_kernel(const float* __restrict__ x, const uint4* __restrict__ xt,
                const int* __restrict__ sqig, const float* __restrict__ w1,
                const float* __restrict__ w2, float* __restrict__ out) {
    const int tid  = threadIdx.x;
    const int lane = tid & 63;
    const int wave = tid >> 6;
    const int b    = blockIdx.x >> 8;           // 256 row-blocks per batch
    const int rblk = blockIdx.x & 255;
    const int n0   = rblk * 16 + wave * RPW;    // 16 rows/block, 4 rows/wave

    const float* xb   = x + (size_t)b * NPTS * DF;
    const int*   sqib = sqig + b * NPTS;
    const uint4* xtb  = xt + (size_t)b * (NG * 2 * 64);

    __shared__ unsigned fifo[4][RPW][FIFO_N];
    __shared__ float    w1n[CC][KNN];
    __shared__ float    w2n[CC][CO];
    __shared__ float    nrm[CC + CO];

    // ---- normalize weights (two barriers, then free-run) ----
    if (tid < CC) {
        float s = 0.f;
        for (int k = 0; k < KNN; ++k) { float v = w1[tid * KNN + k]; s = fmaf(v, v, s); }
        nrm[tid] = sqrtf(s);
    } else if (tid < CC + CO) {
        int o = tid - CC; float s = 0.f;
        for (int c = 0; c < CC; ++c) { float v = w2[c * CO + o]; s = fmaf(v, v, s); }
        nrm[tid] = sqrtf(s);
    }
    __syncthreads();
    if (tid < CC * KNN) w1n[tid >> 4][tid & 15] = w1[tid] / nrm[tid >> 4];
    if (tid < CC * CO)  w2n[tid >> 4][tid & 15] = w2[tid] / nrm[CC + (tid & 15)];
    __syncthreads();                            // weights visible; last barrier

    // ---- 4 rows' i8 fragments straight from xt (bit-identical) ----
    // n0 = rblk*16 + wave*4, so n0&63 <= 60: all 4 rows in one group slab
    unsigned qr[RPW][8];
    {
        const int g0 = n0 >> 6, l0 = n0 & 63;
        const uint4* rp = xtb + (size_t)g0 * 128;
#pragma unroll
        for (int r = 0; r < RPW; ++r) {
            uint4 lo = rp[l0 + r], hi = rp[64 + l0 + r];
            qr[r][0] = lo.x; qr[r][1] = lo.y; qr[r][2] = lo.z; qr[r][3] = lo.w;
            qr[r][4] = hi.x; qr[r][5] = hi.y; qr[r][6] = hi.z; qr[r][7] = hi.w;
        }
    }

    // ---- scan state: 4 independent top-64 lists ----
    unsigned run[RPW] = {0xFFFFFFFFu, 0xFFFFFFFFu, 0xFFFFFFFFu, 0xFFFFFFFFu};
    unsigned T[RPW]   = {0xFFFFFFFFu, 0xFFFFFFFFu, 0xFFFFFFFFu, 0xFFFFFFFFu};
    int base[RPW] = {0,0,0,0}, cnt[RPW] = {0,0,0,0};
    unsigned* ffp[RPW] = { &fifo[wave][0][0], &fifo[wave][1][0],
                           &fifo[wave][2][0], &fifo[wave][3][0] };

    // slim accept (verified R15): same-wave LDS DS ops are in-order
    auto accept = [&](unsigned key, unsigned& rn, unsigned& Th,
                      int& bs, int& ct, unsigned* ff) {
        bool acc = key < Th;
        unsigned long long bal = __ballot(acc);
        if (bal) {                               // wave-uniform
            int pos = ct + (int)__popcll(bal & ((1ull << lane) - 1ull));
            if (acc) ff[(bs + pos) & (FIFO_N - 1)] = key;
            ct += (int)__popcll(bal);
            if (ct >= 64) {                      // at most one merge per call
                asm volatile("" ::: "memory");   // don't hoist the read
                unsigned bk = ff[(bs + lane) & (FIFO_N - 1)];
                bs += 64; ct -= 64;
                merge_batch(rn, bk, lane);
                Th = __shfl(rn, 63);
            }
        }
    };

    // key = ((sqib[m] - 2*dot) >> 2) << 12 | m   (sqib pre-biased by 2^21;
    // integer-exact, range in (0, 2^22) -> 20 bits after >>2)
#define LOADG(d0_, d1_, dsq_, gi)                                            \
    {   const uint4* nb_ = xtb + (size_t)(gi) * 128 + lane;                  \
        d0_ = nb_[0]; d1_ = nb_[64];                                         \
        dsq_ = sqib[(gi) * 64 + lane]; }

#define BODYG(v0_, v1_, vsq_, gi)                                            \
    {   int dt0 = 0, dt1 = 0, dt2 = 0, dt3 = 0;                              \
        dt0 = dot4i8(v0_.x, qr[0][0], dt0);  dt1 = dot4i8(v0_.x, qr[1][0], dt1); \
        dt2 = dot4i8(v0_.x, qr[2][0], dt2);  dt3 = dot4i8(v0_.x, qr[3][0], dt3); \
        dt0 = dot4i8(v0_.y, qr[0][1], dt0);  dt1 = dot4i8(v0_.y, qr[1][1], dt1); \
        dt2 = dot4i8(v0_.y, qr[2][1], dt2);  dt3 = dot4i8(v0_.y, qr[3][1], dt3); \
        dt0 = dot4i8(v0_.z, qr[0][2], dt0);  dt1 = dot4i8(v0_.z, qr[1][2], dt1); \
        dt2 = dot4i8(v0_.z, qr[2][2], dt2);  dt3 = dot4i8(v0_.z, qr[3][2], dt3); \
        dt0 = dot4i8(v0_.w, qr[0][3], dt0);  dt1 = dot4i8(v0_.w, qr[1][3], dt1); \
        dt2 = dot4i8(v0_.w, qr[2][3], dt2);  dt3 = dot4i8(v0_.w, qr[3][3], dt3); \
        dt0 = dot4i8(v1_.x, qr[0][4], dt0);  dt1 = dot4i8(v1_.x, qr[1][4], dt1); \
        dt2 = dot4i8(v1_.x, qr[2][4], dt2);  dt3 = dot4i8(v1_.x, qr[3][4], dt3); \
        dt0 = dot4i8(v1_.y, qr[0][5], dt0);  dt1 = dot4i8(v1_.y, qr[1][5], dt1); \
        dt2 = dot4i8(v1_.y, qr[2][5], dt2);  dt3 = dot4i8(v1_.y, qr[3][5], dt3); \
        dt0 = dot4i8(v1_.z, qr[0][6], dt0);  dt1 = dot4i8(v1_.z, qr[1][6], dt1); \
        dt2 = dot4i8(v1_.z, qr[2][6], dt2);  dt3 = dot4i8(v1_.z, qr[3][6], dt3); \
        dt0 = dot4i8(v1_.w, qr[0][7], dt0);  dt1 = dot4i8(v1_.w, qr[1][7], dt1); \
        dt2 = dot4i8(v1_.w, qr[2][7], dt2);  dt3 = dot4i8(v1_.w, qr[3][7], dt3); \
        unsigned m_ = (unsigned)((gi) * 64 + lane);                          \
        unsigned k0_ = (((unsigned)(vsq_ - 2 * dt0) >> 2) << 12) | m_;       \
        unsigned k1_ = (((unsigned)(vsq_ - 2 * dt1) >> 2) << 12) | m_;       \
        unsigned k2_ = (((unsigned)(vsq_ - 2 * dt2) >> 2) << 12) | m_;       \
        unsigned k3_ = (((unsigned)(vsq_ - 2 * dt3) >> 2) << 12) | m_;       \
        accept(k0_, run[0], T[0], base[0], cnt[0], ffp[0]);                  \
        accept(k1_, run[1], T[1], base[1], cnt[1], ffp[1]);                  \
        accept(k2_, run[2], T[2], base[2], cnt[2], ffp[2]);                  \
        accept(k3_, run[3], T[3], base[3], cnt[3], ffp[3]); }

    // ---- unroll-2 ping-pong: no loop-carried register copies ----
    uint4 a0, a1; int asq;
    uint4 b0, b1; int bsq;
    LOADG(a0, a1, asq, 0);

#pragma unroll 1
    for (int g = 0; g < NG - 2; g += 2) {
        LOADG(b0, b1, bsq, g + 1);
        BODYG(a0, a1, asq, g);
        LOADG(a0, a1, asq, g + 2);
        BODYG(b0, b1, bsq, g + 1);
    }
    // tail: A holds group NG-2
    LOADG(b0, b1, bsq, NG - 1);
    BODYG(a0, a1, asq, NG - 2);
    BODYG(b0, b1, bsq, NG - 1);

#undef LOADG
#undef BODYG

    // ---- drain pending + re-rank + emit, per row ----
#pragma unroll
    for (int r = 0; r < RPW; ++r) {
        if (cnt[r] > 0) {
            asm volatile("" ::: "memory");
            unsigned bk = (lane < cnt[r])
                        ? ffp[r][(base[r] + lane) & (FIFO_N - 1)] : 0xFFFFFFFFu;
            merge_batch(run[r], bk, lane);
        }
        rerank_and_emit(run[r], n0 + r, xb, w1n, w2n, out, b, lane);
    }
}

extern "C" void kernel_launch(void* const* d_in, const int* in_sizes, int n_in,
                              void* d_out, int out_size, void* d_ws, size_t ws_size,
                              hipStream_t stream) {
    const float* x  = (const float*)d_in[0];
    const float* w1 = (const float*)d_in[1];
    const float* w2 = (const float*)d_in[2];
    float* out = (float*)d_out;

    int*   sqi = (int*)d_ws;                                    // 64 KB
    uint4* xt  = (uint4*)((char*)d_ws + (size_t)NB * NPTS * sizeof(int)); // 512 KB

    prep_kernel<<<NB * NPTS / 256, 256, 0, stream>>>(x, sqi, xt);
    wfm_kernel<<<NB * (NPTS / 16), 256, 0, stream>>>(x, xt, sqi, w1, w2, out);
}

// Round 21
// 138.657 us; speedup vs baseline: 1.3109x; 1.3109x over previous
//
#include <hip/hip_runtime.h>

#define NB    4
#define NPTS  4096
#define DF    32      // D*C
#define CC    8
#define CO    16
#define KNN   16
#define NG    (NPTS/64)   // 64 candidate groups per batch
#define FIFO_N 128    // per-row pending ring (max pending 63+64=127)
#define QS    21.0f   // i8 quant scale (127/6 sigma; data N(0,1), no clipping)
#define BIAS  (1 << 21)

__device__ __forceinline__ int q8(float x) {
    int v = __float2int_rn(x * QS);
    return v < -127 ? -127 : (v > 127 ? 127 : v);
}
__device__ __forceinline__ int dot4i8(unsigned a, unsigned b, int acc) {
#if __has_builtin(__builtin_amdgcn_sdot4)
    return __builtin_amdgcn_sdot4((int)a, (int)b, acc, false);
#else
    int s = acc;
#pragma unroll
    for (int i = 0; i < 4; ++i)
        s += (int)(char)((a >> (8 * i)) & 255) * (int)(char)((b >> (8 * i)) & 255);
    return s;
#endif
}

// Full-wave ascending bitonic sort of one u32 per lane (verified R3-R19).
__device__ __forceinline__ unsigned bitonic_sort64(unsigned key, int lane) {
#pragma unroll
    for (int k = 2; k <= 64; k <<= 1) {
#pragma unroll
        for (int j = k >> 1; j > 0; j >>= 1) {
            unsigned o = __shfl_xor(key, j);
            bool up       = ((lane & k) == 0);
            bool lower    = ((lane & j) == 0);
            bool takeMin  = (lower == up);
            bool mineLess = key < o;
            if (takeMin != mineLess) key = o;
        }
    }
    return key;
}
__device__ __forceinline__ unsigned bitonic_clean64(unsigned v, int lane) {
#pragma unroll
    for (int j = 32; j > 0; j >>= 1) {
        unsigned o = __shfl_xor(v, j);
        bool lower = ((lane & j) == 0);
        v = lower ? min(v, o) : max(v, o);
    }
    return v;
}
__device__ __forceinline__ void merge_batch(unsigned& run, unsigned bk, int lane) {
    bk = bitonic_sort64(bk, lane);
    unsigned rev = __shfl(bk, 63 - lane);
    unsigned lo  = min(run, rev);
    run = bitonic_clean64(lo, lane);
}

// ---- prep: pre-biased integer sq + group-transposed i8 layout ----
__global__ void prep_kernel(const float* __restrict__ x, int* __restrict__ sqi,
                            uint4* __restrict__ xt) {
    int i = blockIdx.x * 256 + threadIdx.x;          // 0 .. NB*NPTS-1
    const int b = i >> 12, n = i & (NPTS - 1);
    const int g = n >> 6,  l = n & 63;
    const float* p = x + (size_t)i * DF;
    int s = 0;
    unsigned pk[8];
#pragma unroll
    for (int j = 0; j < 8; ++j) {
        int q0 = q8(p[4*j+0]), q1 = q8(p[4*j+1]);
        int q2 = q8(p[4*j+2]), q3 = q8(p[4*j+3]);
        s += q0*q0 + q1*q1 + q2*q2 + q3*q3;
        pk[j] = (unsigned)(q0 & 255) | ((unsigned)(q1 & 255) << 8)
              | ((unsigned)(q2 & 255) << 16) | ((unsigned)(q3 & 255) << 24);
    }
    uint4* ho = xt + ((size_t)(b * NG + g) * 2) * 64 + l;
    ho[0]  = make_uint4(pk[0], pk[1], pk[2], pk[3]);
    ho[64] = make_uint4(pk[4], pk[5], pk[6], pk[7]);
    sqi[i] = s + BIAS;                   // pre-biased: key_d = sqi - 2*dot > 0
}

// ---- canonical-fp32 re-rank + output (verified R3-R19 verbatim) ----
__device__ __forceinline__ void rerank_and_emit(
    unsigned runv, int nn, const float* __restrict__ xb,
    const float (*w1n)[KNN], const float (*w2n)[CO],
    float* __restrict__ out, int bb, int lane) {

    int mym = (int)(runv & 0xFFFu);
    const float* rp = xb + (size_t)nn * DF;
    const float* cp = xb + (size_t)mym * DF;
    double dot64 = 0.0, sqm64 = 0.0, sqn64 = 0.0;
#pragma unroll
    for (int f = 0; f < DF; ++f) {
        double cv = (double)cp[f];
        double rv = (double)rp[f];
        dot64 = fma(rv, cv, dot64);
        sqm64 = fma(cv, cv, sqm64);
        sqn64 = fma(rv, rv, sqn64);
    }
    float dist32 = ((float)sqn64 + (float)sqm64) - 2.0f * (float)dot64;

    unsigned sortd;
    {
        unsigned u = __float_as_uint(dist32);
        sortd = u ^ ((unsigned)((int)u >> 31) | 0x80000000u);
    }
    unsigned long long key =
        ((unsigned long long)sortd << 32) | (unsigned)mym;
#pragma unroll
    for (int k = 2; k <= 64; k <<= 1) {
#pragma unroll
        for (int j = k >> 1; j > 0; j >>= 1) {
            unsigned long long ok = __shfl_xor(key, j);
            bool up       = ((lane & k) == 0);
            bool lower    = ((lane & j) == 0);
            bool takeMin  = (lower == up);
            bool mineLess = (key < ok);
            if (takeMin != mineLess) key = ok;
        }
    }
    mym = (int)(key & 0xFFFFFFFFull);

    float wsum = 0.f;
#pragma unroll
    for (int k = 0; k < KNN; ++k) {
        int mk = __shfl(mym, k);                       // uniform
        float v = 0.f;
        if (lane < DF) v = xb[(size_t)mk * DF + lane]; // coalesced gather
        wsum = fmaf(v, w1n[lane & 7][k], wsum);        // lane = d*8+c
    }
    float ov = 0.f;
    const int d_ = lane >> 4, o_ = lane & 15;
#pragma unroll
    for (int c = 0; c < CC; ++c) {
        float wv = __shfl(wsum, d_ * CC + c);
        ov = fmaf(wv, w2n[c][o_], ov);
    }
    out[(size_t)(bb * NPTS + nn) * (4 * CO) + lane] = ov;
}

// ============ barrier-free i8 scan, slim accept (champion) =================
__global__ __launch_bounds__(256)
void wfm_kernel(const float* __restrict__ x, const uint4* __restrict__ xt,
                const int* __restrict__ sqig, const float* __restrict__ w1,
                const float* __restrict__ w2, float* __restrict__ out) {
    const int tid  = threadIdx.x;
    const int lane = tid & 63;
    const int wave = tid >> 6;
    const int b    = blockIdx.x >> 9;           // 512 row-blocks per batch
    const int rblk = blockIdx.x & 511;
    const int n0   = rblk * 8 + wave * 2;       // 8 rows/block, 2 rows/wave

    const float* xb   = x + (size_t)b * NPTS * DF;
    const int*   sqib = sqig + b * NPTS;
    const uint4* xtb  = xt + (size_t)b * (NG * 2 * 64);

    __shared__ unsigned fifo[4][2][FIFO_N];
    __shared__ float    w1n[CC][KNN];
    __shared__ float    w2n[CC][CO];
    __shared__ float    nrm[CC + CO];

    // ---- normalize weights (two barriers, then free-run) ----
    if (tid < CC) {
        float s = 0.f;
        for (int k = 0; k < KNN; ++k) { float v = w1[tid * KNN + k]; s = fmaf(v, v, s); }
        nrm[tid] = sqrtf(s);
    } else if (tid < CC + CO) {
        int o = tid - CC; float s = 0.f;
        for (int c = 0; c < CC; ++c) { float v = w2[c * CO + o]; s = fmaf(v, v, s); }
        nrm[tid] = sqrtf(s);
    }
    __syncthreads();
    if (tid < CC * KNN) w1n[tid >> 4][tid & 15] = w1[tid] / nrm[tid >> 4];
    if (tid < CC * CO)  w2n[tid >> 4][tid & 15] = w2[tid] / nrm[CC + (tid & 15)];
    __syncthreads();                            // weights visible; last barrier

    // ---- row i8 fragments straight from xt (bit-identical to candidates) ----
    unsigned qr0[8], qr1[8];
    {
        const int g0 = n0 >> 6, l0 = n0 & 63;          // rows n0, n0+1 same group
        const uint4* rp = xtb + (size_t)g0 * 128;
        uint4 a0 = rp[l0],     a1 = rp[64 + l0];       // row n0: chunks 0-3, 4-7
        uint4 c0 = rp[l0 + 1], c1 = rp[64 + l0 + 1];   // row n0+1
        qr0[0] = a0.x; qr0[1] = a0.y; qr0[2] = a0.z; qr0[3] = a0.w;
        qr0[4] = a1.x; qr0[5] = a1.y; qr0[6] = a1.z; qr0[7] = a1.w;
        qr1[0] = c0.x; qr1[1] = c0.y; qr1[2] = c0.z; qr1[3] = c0.w;
        qr1[4] = c1.x; qr1[5] = c1.y; qr1[6] = c1.z; qr1[7] = c1.w;
    }

    // ---- scan state ----
    unsigned run0 = 0xFFFFFFFFu, run1 = 0xFFFFFFFFu;
    unsigned T0 = 0xFFFFFFFFu,   T1 = 0xFFFFFFFFu;
    int base0 = 0, cnt0 = 0, base1 = 0, cnt1 = 0;
    unsigned* ff0 = &fifo[wave][0][0];
    unsigned* ff1 = &fifo[wave][1][0];

    // slim accept: same-wave LDS DS ops are in-order; only a compiler
    // reorder guard is needed before the merge's FIFO read.
    auto accept = [&](unsigned key, unsigned& run, unsigned& T,
                      int& base, int& cnt, unsigned* ff) {
        bool acc = key < T;
        unsigned long long bal = __ballot(acc);
        if (bal) {                               // wave-uniform
            int pos = cnt + (int)__popcll(bal & ((1ull << lane) - 1ull));
            if (acc) ff[(base + pos) & (FIFO_N - 1)] = key;
            cnt += (int)__popcll(bal);
            if (cnt >= 64) {                     // at most one merge per call
                asm volatile("" ::: "memory");   // don't hoist the read
                unsigned bk = ff[(base + lane) & (FIFO_N - 1)];
                base += 64; cnt -= 64;
                merge_batch(run, bk, lane);
                T = __shfl(run, 63);
            }
        }
    };

    // key = ((sqib[m] - 2*dot) >> 2) << 12 | m   (sqib pre-biased by 2^21;
    // integer-exact, range [1.06M, 3.65M] -> 20 bits after >>2)
#define LOADG(d0_, d1_, dsq_, gi)                                            \
    {   const uint4* nb_ = xtb + (size_t)(gi) * 128 + lane;                  \
        d0_ = nb_[0]; d1_ = nb_[64];                                         \
        dsq_ = sqib[(gi) * 64 + lane]; }

#define BODYG(v0_, v1_, vsq_, gi)                                            \
    {   int dt0 = 0, dt1 = 0;                                                \
        dt0 = dot4i8(v0_.x, qr0[0], dt0);  dt1 = dot4i8(v0_.x, qr1[0], dt1); \
        dt0 = dot4i8(v0_.y, qr0[1], dt0);  dt1 = dot4i8(v0_.y, qr1[1], dt1); \
        dt0 = dot4i8(v0_.z, qr0[2], dt0);  dt1 = dot4i8(v0_.z, qr1[2], dt1); \
        dt0 = dot4i8(v0_.w, qr0[3], dt0);  dt1 = dot4i8(v0_.w, qr1[3], dt1); \
        dt0 = dot4i8(v1_.x, qr0[4], dt0);  dt1 = dot4i8(v1_.x, qr1[4], dt1); \
        dt0 = dot4i8(v1_.y, qr0[5], dt0);  dt1 = dot4i8(v1_.y, qr1[5], dt1); \
        dt0 = dot4i8(v1_.z, qr0[6], dt0);  dt1 = dot4i8(v1_.z, qr1[6], dt1); \
        dt0 = dot4i8(v1_.w, qr0[7], dt0);  dt1 = dot4i8(v1_.w, qr1[7], dt1); \
        unsigned m_ = (unsigned)((gi) * 64 + lane);                          \
        unsigned k0_ = (((unsigned)(vsq_ - 2 * dt0) >> 2) << 12) | m_;       \
        unsigned k1_ = (((unsigned)(vsq_ - 2 * dt1) >> 2) << 12) | m_;       \
        accept(k0_, run0, T0, base0, cnt0, ff0);                             \
        accept(k1_, run1, T1, base1, cnt1, ff1); }

    // ---- unroll-2 ping-pong: no loop-carried register copies ----
    uint4 a0, a1; int asq;
    uint4 b0, b1; int bsq;
    LOADG(a0, a1, asq, 0);

#pragma unroll 1
    for (int g = 0; g < NG - 2; g += 2) {
        LOADG(b0, b1, bsq, g + 1);
        BODYG(a0, a1, asq, g);
        LOADG(a0, a1, asq, g + 2);
        BODYG(b0, b1, bsq, g + 1);
    }
    // tail: A holds group NG-2
    LOADG(b0, b1, bsq, NG - 1);
    BODYG(a0, a1, asq, NG - 2);
    BODYG(b0, b1, bsq, NG - 1);

#undef LOADG
#undef BODYG

    // ---- drain pending (pad with +inf) ----
    if (cnt0 > 0) {
        asm volatile("" ::: "memory");
        unsigned bk = (lane < cnt0) ? ff0[(base0 + lane) & (FIFO_N - 1)] : 0xFFFFFFFFu;
        merge_batch(run0, bk, lane);
    }
    if (cnt1 > 0) {
        asm volatile("" ::: "memory");
        unsigned bk = (lane < cnt1) ? ff1[(base1 + lane) & (FIFO_N - 1)] : 0xFFFFFFFFu;
        merge_batch(run1, bk, lane);
    }

    rerank_and_emit(run0, n0 + 0, xb, w1n, w2n, out, b, lane);
    rerank_and_emit(run1, n0 + 1, xb, w1n, w2n, out, b, lane);
}

extern "C" void kernel_launch(void* const* d_in, const int* in_sizes, int n_in,
                              void* d_out, int out_size, void* d_ws, size_t ws_size,
                              hipStream_t stream) {
    const float* x  = (const float*)d_in[0];
    const float* w1 = (const float*)d_in[1];
    const float* w2 = (const float*)d_in[2];
    float* out = (float*)d_out;

    int*   sqi = (int*)d_ws;                                    // 64 KB
    uint4* xt  = (uint4*)((char*)d_ws + (size_t)NB * NPTS * sizeof(int)); // 512 KB

    prep_kernel<<<NB * NPTS / 256, 256, 0, stream>>>(x, sqi, xt);
    wfm_kernel<<<NB * (NPTS / 8), 256, 0, stream>>>(x, xt, sqi, w1, w2, out);
}